// Round 2
// baseline (669.826 us; speedup 1.0000x reference)
//
#include <hip/hip_runtime.h>
#include <hip/hip_bf16.h>

typedef unsigned short u16_t;
typedef unsigned int   u32_t;

#define B_ROWS  16384
#define D_IN    1024
#define D_OUT   512
#define NEXP    16
#define EPSF    2.2204460492503131e-16f

using short8  = __attribute__((ext_vector_type(8))) short;
using floatx4 = __attribute__((ext_vector_type(4))) float;

__device__ __forceinline__ u16_t f2bf(float f) {
    u32_t u = __float_as_uint(f);
    u += 0x7fffu + ((u >> 16) & 1u);        // round-to-nearest-even
    return (u16_t)(u >> 16);
}

// ---------------------------------------------------------------------------
// Transpose w_router [D_IN][E] -> wrT [E][D_IN] so router lanes can stream
// contiguous float4s. 64 KB total, L2-resident afterwards.
// ---------------------------------------------------------------------------
__global__ __launch_bounds__(256) void transpose_wr(
        const float* __restrict__ wr, float* __restrict__ wrT) {
    int i = blockIdx.x * 256 + threadIdx.x;      // i = e*D_IN + d
    int e = i >> 10, d = i & 1023;
    wrT[i] = wr[d * NEXP + e];
}

// ---------------------------------------------------------------------------
// Router: one wave per row. Lane (e = lane&15, q = lane>>4) accumulates a
// quarter of the f64 dot product for expert e with 4 independent partials
// (breaks the serial FMA chain — R1 post-mortem: 403us latency-bound) and
// float4 vector loads from x and the transposed router weights.
// f64 so expert selection matches the high-precision np reference.
// ---------------------------------------------------------------------------
__global__ __launch_bounds__(256) void router_kernel(
        const float* __restrict__ x, const float* __restrict__ wrT,
        int* __restrict__ counts, int* __restrict__ rowlist,
        float* __restrict__ gatelist) {
    int wave = threadIdx.x >> 6;
    int lane = threadIdx.x & 63;
    int b = blockIdx.x * 4 + wave;
    int e = lane & 15, q = lane >> 4;

    const float4* xq = (const float4*)(x + (size_t)b * D_IN + q * 256);
    const float4* wq = (const float4*)(wrT + (size_t)e * D_IN + q * 256);

    double a0 = 0.0, a1 = 0.0, a2 = 0.0, a3 = 0.0;
    #pragma unroll 8
    for (int i = 0; i < 64; ++i) {
        float4 xv = xq[i];
        float4 wv = wq[i];
        a0 += (double)xv.x * (double)wv.x;
        a1 += (double)xv.y * (double)wv.y;
        a2 += (double)xv.z * (double)wv.z;
        a3 += (double)xv.w * (double)wv.w;
    }
    double acc = (a0 + a1) + (a2 + a3);

    acc += __shfl_xor(acc, 16);
    acc += __shfl_xor(acc, 32);
    // lanes 0..15 now hold logits[e]; broadcast-scan for top-2 (all lanes)
    int i1 = -1; double v1 = -1e300;
    for (int ee = 0; ee < NEXP; ++ee) {
        double t = __shfl(acc, ee);
        if (t > v1) { v1 = t; i1 = ee; }
    }
    int i2 = -1; double v2 = -1e300;
    for (int ee = 0; ee < NEXP; ++ee) {
        double t = __shfl(acc, ee);
        if (ee != i1 && t > v2) { v2 = t; i2 = ee; }
    }
    if (lane == 0) {
        double ed = exp(v2 - v1);          // <= 1
        double s = 1.0 + ed;
        float g1 = (float)(1.0 / s);
        float g2 = (float)(ed / s);
        int p1 = atomicAdd(&counts[i1], 1);
        rowlist[i1 * B_ROWS + p1] = (b << 1);
        gatelist[i1 * B_ROWS + p1] = g1;
        int p2 = atomicAdd(&counts[i2], 1);
        rowlist[i2 * B_ROWS + p2] = (b << 1) | 1;
        gatelist[i2 * B_ROWS + p2] = g2;
    }
}

// ---------------------------------------------------------------------------
// Grouped expert GEMM, 128x128 tile, BK=32, bf16 MFMA 16x16x32, 4 waves in
// 2x2; epilogue applies gate*exp and stores per-slot (contrib path) or
// atomicAdds into out (fallback).
// ---------------------------------------------------------------------------
template<bool USE_CONTRIB>
__global__ __launch_bounds__(256) void moe_gemm(
        const float* __restrict__ x, const float* __restrict__ w,
        const int* __restrict__ counts, const int* __restrict__ rowlist,
        const float* __restrict__ gatelist,
        float* __restrict__ out, float* __restrict__ contrib) {
    int e = blockIdx.z;
    int n_e = counts[e];
    int ty = blockIdx.y;
    if (ty * 128 >= n_e) return;
    int n0 = blockIdx.x * 128;

    __shared__ u16_t Ash[128][40];   // [m][k] bf16, pad 32->40
    __shared__ u32_t Bsh[16][132];   // [k-pair][n] packed bf16x2, pad 128->132
    __shared__ int   rid_sh[128];
    __shared__ float gt_sh[128];

    int t = threadIdx.x;
    if (t < 128) {
        int gi = ty * 128 + t;
        int v = 0; float g = 0.f;
        if (gi < n_e) { v = rowlist[e * B_ROWS + gi]; g = gatelist[e * B_ROWS + gi]; }
        rid_sh[t] = v; gt_sh[t] = g;
    }
    __syncthreads();

    // staging assignments
    int ar = t >> 1, ah = t & 1;                 // A: row, k-half
    const float* xptr = x + (size_t)(rid_sh[ar] >> 1) * D_IN + ah * 16;
    int bkp = t >> 4, bng = t & 15;              // B: k-pair, n-group of 8
    const float* wptr = w + (size_t)e * (D_IN * D_OUT)
                          + (size_t)(2 * bkp) * D_OUT + n0 + bng * 8;

    int lane = t & 63, wv = t >> 6;
    int wm = wv >> 1, wn = wv & 1;
    int lm = lane & 15, q = lane >> 4;

    floatx4 acc[4][4];
    #pragma unroll
    for (int mi = 0; mi < 4; ++mi)
        #pragma unroll
        for (int ni = 0; ni < 4; ++ni)
            acc[mi][ni] = (floatx4){0.f, 0.f, 0.f, 0.f};

    for (int it = 0; it < D_IN / 32; ++it) {
        float4 av0 = *(const float4*)(xptr + 0);
        float4 av1 = *(const float4*)(xptr + 4);
        float4 av2 = *(const float4*)(xptr + 8);
        float4 av3 = *(const float4*)(xptr + 12);
        xptr += 32;
        float4 b0 = *(const float4*)(wptr + 0);
        float4 b1 = *(const float4*)(wptr + 4);
        float4 b2 = *(const float4*)(wptr + D_OUT);
        float4 b3 = *(const float4*)(wptr + D_OUT + 4);
        wptr += 32 * D_OUT;

        __syncthreads();   // prev iter's LDS reads done
        {
            union { u16_t us[16]; uint4 v[2]; } ap;
            float af[16] = {av0.x, av0.y, av0.z, av0.w, av1.x, av1.y, av1.z, av1.w,
                            av2.x, av2.y, av2.z, av2.w, av3.x, av3.y, av3.z, av3.w};
            #pragma unroll
            for (int j = 0; j < 16; ++j) ap.us[j] = f2bf(af[j]);
            *(uint4*)(&Ash[ar][ah * 16])     = ap.v[0];
            *(uint4*)(&Ash[ar][ah * 16 + 8]) = ap.v[1];
        }
        {
            union { u32_t up[8]; uint4 v[2]; } bp;
            bp.up[0] = (u32_t)f2bf(b0.x) | ((u32_t)f2bf(b2.x) << 16);
            bp.up[1] = (u32_t)f2bf(b0.y) | ((u32_t)f2bf(b2.y) << 16);
            bp.up[2] = (u32_t)f2bf(b0.z) | ((u32_t)f2bf(b2.z) << 16);
            bp.up[3] = (u32_t)f2bf(b0.w) | ((u32_t)f2bf(b2.w) << 16);
            bp.up[4] = (u32_t)f2bf(b1.x) | ((u32_t)f2bf(b3.x) << 16);
            bp.up[5] = (u32_t)f2bf(b1.y) | ((u32_t)f2bf(b3.y) << 16);
            bp.up[6] = (u32_t)f2bf(b1.z) | ((u32_t)f2bf(b3.z) << 16);
            bp.up[7] = (u32_t)f2bf(b1.w) | ((u32_t)f2bf(b3.w) << 16);
            *(uint4*)(&Bsh[bkp][bng * 8])     = bp.v[0];
            *(uint4*)(&Bsh[bkp][bng * 8 + 4]) = bp.v[1];
        }
        __syncthreads();

        short8 afr[4];
        #pragma unroll
        for (int mi = 0; mi < 4; ++mi)
            afr[mi] = *(const short8*)(&Ash[wm * 64 + mi * 16 + lm][q * 8]);
        short8 bfr[4];
        #pragma unroll
        for (int ni = 0; ni < 4; ++ni) {
            int nn = wn * 64 + ni * 16 + lm;
            union { uint4 u; short8 s; } cv;
            cv.u.x = Bsh[q * 4 + 0][nn];
            cv.u.y = Bsh[q * 4 + 1][nn];
            cv.u.z = Bsh[q * 4 + 2][nn];
            cv.u.w = Bsh[q * 4 + 3][nn];
            bfr[ni] = cv.s;
        }
        #pragma unroll
        for (int mi = 0; mi < 4; ++mi)
            #pragma unroll
            for (int ni = 0; ni < 4; ++ni)
                acc[mi][ni] = __builtin_amdgcn_mfma_f32_16x16x32_bf16(
                    afr[mi], bfr[ni], acc[mi][ni], 0, 0, 0);
    }

    // epilogue: C/D layout col=lane&15, row=(lane>>4)*4+reg
    #pragma unroll
    for (int mi = 0; mi < 4; ++mi) {
        int rbase = wm * 64 + mi * 16 + q * 4;
        #pragma unroll
        for (int r = 0; r < 4; ++r) {
            int row = rbase + r;
            int gi = ty * 128 + row;
            bool ok = gi < n_e;
            int v = rid_sh[row];
            float g = gt_sh[row];
            size_t orow = (size_t)(v >> 1) * D_OUT;
            #pragma unroll
            for (int ni = 0; ni < 4; ++ni) {
                int c = n0 + wn * 64 + ni * 16 + lm;
                float val = g * __expf(acc[mi][ni][r]);
                if (ok) {
                    if (USE_CONTRIB) {
                        float* dst = (v & 1) ? contrib : out;
                        dst[orow + c] = val;
                    } else {
                        atomicAdd(&out[orow + c], val);
                    }
                }
            }
        }
    }
}

// ---------------------------------------------------------------------------
// Combine: out = log(clamp(slot0 + slot1, eps))
// ---------------------------------------------------------------------------
__global__ __launch_bounds__(256) void combine_add_log(
        float* __restrict__ out, const float* __restrict__ contrib, int n4) {
    int i = blockIdx.x * blockDim.x + threadIdx.x;
    if (i >= n4) return;
    float4 a = ((const float4*)out)[i];
    float4 b = ((const float4*)contrib)[i];
    float4 r;
    float s;
    s = a.x + b.x; s = (s == 0.f) ? EPSF : s; r.x = __logf(s);
    s = a.y + b.y; s = (s == 0.f) ? EPSF : s; r.y = __logf(s);
    s = a.z + b.z; s = (s == 0.f) ? EPSF : s; r.z = __logf(s);
    s = a.w + b.w; s = (s == 0.f) ? EPSF : s; r.w = __logf(s);
    ((float4*)out)[i] = r;
}

__global__ __launch_bounds__(256) void log_inplace(float* __restrict__ out, int n4) {
    int i = blockIdx.x * blockDim.x + threadIdx.x;
    if (i >= n4) return;
    float4 a = ((float4*)out)[i];
    float4 r;
    float s;
    s = a.x; s = (s == 0.f) ? EPSF : s; r.x = __logf(s);
    s = a.y; s = (s == 0.f) ? EPSF : s; r.y = __logf(s);
    s = a.z; s = (s == 0.f) ? EPSF : s; r.z = __logf(s);
    s = a.w; s = (s == 0.f) ? EPSF : s; r.w = __logf(s);
    ((float4*)out)[i] = r;
}

extern "C" void kernel_launch(void* const* d_in, const int* in_sizes, int n_in,
                              void* d_out, int out_size, void* d_ws, size_t ws_size,
                              hipStream_t stream) {
    const float* x  = (const float*)d_in[0];
    const float* wr = (const float*)d_in[1];
    const float* we = (const float*)d_in[2];
    float* out = (float*)d_out;
    char* ws = (char*)d_ws;

    int*   counts  = (int*)ws;                                  // 256 B
    int*   rowlist = (int*)(ws + 256);                          // 1 MB
    float* gates   = (float*)(ws + 256 + (size_t)NEXP * B_ROWS * 4);  // 1 MB
    size_t wtbase  = 256 + 2ull * NEXP * B_ROWS * 4;
    float* wrT     = (float*)(ws + wtbase);                     // 64 KB
    size_t cbase   = wtbase + (size_t)NEXP * D_IN * 4;
    float* contrib = (float*)(ws + cbase);                      // 32 MB (optional)
    bool use_contrib = ws_size >= cbase + (size_t)B_ROWS * D_OUT * 4;

    hipMemsetAsync(counts, 0, 64, stream);
    transpose_wr<<<NEXP * D_IN / 256, 256, 0, stream>>>(wr, wrT);
    router_kernel<<<B_ROWS / 4, 256, 0, stream>>>(x, wrT, counts, rowlist, gates);

    dim3 g(D_OUT / 128, B_ROWS / 128, NEXP);
    int n4 = B_ROWS * D_OUT / 4;
    if (use_contrib) {
        moe_gemm<true><<<g, 256, 0, stream>>>(x, we, counts, rowlist, gates, out, contrib);
        combine_add_log<<<(n4 + 255) / 256, 256, 0, stream>>>(out, contrib, n4);
    } else {
        hipMemsetAsync(out, 0, (size_t)B_ROWS * D_OUT * 4, stream);
        moe_gemm<false><<<g, 256, 0, stream>>>(x, we, counts, rowlist, gates, out, nullptr);
        log_inplace<<<(n4 + 255) / 256, 256, 0, stream>>>(out, n4);
    }
}

// Round 3
// 272.511 us; speedup vs baseline: 2.4580x; 2.4580x over previous
//
#include <hip/hip_runtime.h>
#include <hip/hip_bf16.h>

typedef unsigned short u16_t;
typedef unsigned int   u32_t;

#define B_ROWS  16384
#define D_IN    1024
#define D_OUT   512
#define NEXP    16
#define CNT_STRIDE 16   // pad each expert counter to its own 64B line (R2 post-mortem)
#define EPSF    2.2204460492503131e-16f

using short8  = __attribute__((ext_vector_type(8))) short;
using floatx4 = __attribute__((ext_vector_type(4))) float;

__device__ __forceinline__ u16_t f2bf(float f) {
    u32_t u = __float_as_uint(f);
    u += 0x7fffu + ((u >> 16) & 1u);        // round-to-nearest-even
    return (u16_t)(u >> 16);
}

// ---------------------------------------------------------------------------
// Transpose w_router [D_IN][E] -> wrT [E][D_IN] f32 (64 KB).
// ---------------------------------------------------------------------------
__global__ __launch_bounds__(256) void transpose_wr(
        const float* __restrict__ wr, float* __restrict__ wrT) {
    int i = blockIdx.x * 256 + threadIdx.x;      // i = e*D_IN + d
    int e = i >> 10, d = i & 1023;
    wrT[i] = wr[d * NEXP + e];
}

// ---------------------------------------------------------------------------
// x f32 -> bf16 (row-major unchanged). 8 elems/thread.
// ---------------------------------------------------------------------------
__global__ __launch_bounds__(256) void convert_x(
        const float* __restrict__ x, u16_t* __restrict__ xb) {
    size_t i = ((size_t)blockIdx.x * 256 + threadIdx.x) * 8;
    float4 a = *(const float4*)(x + i);
    float4 b = *(const float4*)(x + i + 4);
    union { u16_t us[8]; uint4 v; } p;
    p.us[0] = f2bf(a.x); p.us[1] = f2bf(a.y); p.us[2] = f2bf(a.z); p.us[3] = f2bf(a.w);
    p.us[4] = f2bf(b.x); p.us[5] = f2bf(b.y); p.us[6] = f2bf(b.z); p.us[7] = f2bf(b.w);
    *(uint4*)(xb + i) = p.v;
}

// ---------------------------------------------------------------------------
// w_experts [e][k][n] f32 -> wT [e][n][k] bf16. Loads coalesced across n
// (lane = n); store is one uint4 per lane (scattered 16B, acceptable).
// ---------------------------------------------------------------------------
__global__ __launch_bounds__(256) void convert_wT(
        const float* __restrict__ w, u16_t* __restrict__ wT) {
    int b = blockIdx.x;
    int e  = b >> 8;
    int k0 = ((b >> 1) & 127) * 8;
    int n  = (b & 1) * 256 + threadIdx.x;
    const float* src = w + ((size_t)e * D_IN + k0) * D_OUT + n;
    union { u16_t us[8]; uint4 v; } p;
    #pragma unroll
    for (int j = 0; j < 8; ++j) p.us[j] = f2bf(src[(size_t)j * D_OUT]);
    *(uint4*)(wT + ((size_t)e * D_OUT + n) * D_IN + k0) = p.v;
}

// ---------------------------------------------------------------------------
// Router v3: 32 rows/block, 256 threads (thread = (row lr=t>>3, oct q=t&7)),
// wrT staged in LDS (64 KB, q-swizzled reads -> conflict-free broadcast).
// f64 dots (exact top-2 vs np ref). Atomics hierarchized: LDS histogram ->
// 16 line-padded global atomics per block -> LDS-ordered scatter.
// ---------------------------------------------------------------------------
__global__ __launch_bounds__(256) void router_kernel(
        const float* __restrict__ x, const float* __restrict__ wrT,
        int* __restrict__ counts, int* __restrict__ rowlist,
        float* __restrict__ gatelist) {
    __shared__ float wsh[NEXP * D_IN];          // 64 KB [e][d]
    __shared__ int hist[NEXP], base[NEXP], hist2[NEXP];
    __shared__ unsigned char eidx_sh[32][2];
    __shared__ float g_sh[32][2];

    int t = threadIdx.x;
    {   // stage wrT: 16384 floats / 256 threads = 16 float4 each
        const float4* src = (const float4*)wrT;
        float4* dst = (float4*)wsh;
        #pragma unroll
        for (int i = 0; i < 16; ++i) dst[t + 256 * i] = src[t + 256 * i];
    }
    if (t < NEXP) { hist[t] = 0; hist2[t] = 0; }
    __syncthreads();

    int lr = t >> 3, q = t & 7;
    int row = blockIdx.x * 32 + lr;
    const float4* xq = (const float4*)(x + (size_t)row * D_IN + q * 128);

    double acc[NEXP];
    #pragma unroll
    for (int e = 0; e < NEXP; ++e) acc[e] = 0.0;

    for (int i = 0; i < 32; ++i) {
        int ii = (i + q * 4) & 31;              // rotate start by q: LDS banks disjoint
        float4 xv = xq[ii];
        double x0 = xv.x, x1 = xv.y, x2 = xv.z, x3 = xv.w;
        int d = q * 128 + ii * 4;
        #pragma unroll
        for (int e = 0; e < NEXP; ++e) {
            float4 wv = *(const float4*)(&wsh[e * D_IN + d]);
            acc[e] += x0 * (double)wv.x;
            acc[e] += x1 * (double)wv.y;
            acc[e] += x2 * (double)wv.z;
            acc[e] += x3 * (double)wv.w;
        }
    }
    #pragma unroll
    for (int e = 0; e < NEXP; ++e) {
        acc[e] += __shfl_xor(acc[e], 1);
        acc[e] += __shfl_xor(acc[e], 2);
        acc[e] += __shfl_xor(acc[e], 4);
    }
    if (q == 0) {
        // top-2, stable (lower index wins ties) == jax.lax.top_k
        int i1 = 0; double v1 = acc[0];
        #pragma unroll
        for (int e = 1; e < NEXP; ++e) if (acc[e] > v1) { v1 = acc[e]; i1 = e; }
        int i2 = -1; double v2 = -1.0e300;
        #pragma unroll
        for (int e = 0; e < NEXP; ++e) if (e != i1 && acc[e] > v2) { v2 = acc[e]; i2 = e; }
        double ed = exp(v2 - v1);               // <= 1
        double s = 1.0 + ed;
        eidx_sh[lr][0] = (unsigned char)i1; g_sh[lr][0] = (float)(1.0 / s);
        eidx_sh[lr][1] = (unsigned char)i2; g_sh[lr][1] = (float)(ed / s);
        atomicAdd(&hist[i1], 1);
        atomicAdd(&hist[i2], 1);
    }
    __syncthreads();
    if (t < NEXP) base[t] = atomicAdd(&counts[t * CNT_STRIDE], hist[t]);
    __syncthreads();
    if (t < 64) {
        int r = t >> 1, sl = t & 1;
        int e = eidx_sh[r][sl];
        int pos = base[e] + atomicAdd(&hist2[e], 1);
        rowlist[e * B_ROWS + pos] = ((blockIdx.x * 32 + r) << 1) | sl;
        gatelist[e * B_ROWS + pos] = g_sh[r][sl];
    }
}

// ---------------------------------------------------------------------------
// Grouped expert GEMM from pre-converted bf16 (x row-major, wT [e][n][k]).
// 128x128 tile, BK=32, mfma 16x16x32 bf16, 2x2 waves. Staging: 4 uint4 loads
// + 4 ds_write_b128 per thread/iter (no f32->bf16 in the hot loop).
// ---------------------------------------------------------------------------
template<bool USE_CONTRIB>
__global__ __launch_bounds__(256) void moe_gemm_bf16(
        const u16_t* __restrict__ xb, const u16_t* __restrict__ wT,
        const int* __restrict__ counts, const int* __restrict__ rowlist,
        const float* __restrict__ gatelist,
        float* __restrict__ out, float* __restrict__ contrib) {
    int e = blockIdx.z;
    int n_e = counts[e * CNT_STRIDE];
    int ty = blockIdx.y;
    if (ty * 128 >= n_e) return;
    int n0 = blockIdx.x * 128;

    __shared__ u16_t Ash[128][40];   // [m][k], stride 80B: 16B-aligned rows
    __shared__ u16_t Bsh[128][40];   // [n][k], same
    __shared__ int   rid_sh[128];
    __shared__ float gt_sh[128];

    int t = threadIdx.x;
    if (t < 128) {
        int gi = ty * 128 + t;
        int v = 0; float g = 0.f;
        if (gi < n_e) { v = rowlist[e * B_ROWS + gi]; g = gatelist[e * B_ROWS + gi]; }
        rid_sh[t] = v; gt_sh[t] = g;
    }
    __syncthreads();

    int hr = t >> 1, hh = t & 1;     // half-row assignment for both A and B
    const u16_t* aptr = xb + (size_t)(rid_sh[hr] >> 1) * D_IN + hh * 16;
    const u16_t* bptr = wT + ((size_t)e * D_OUT + n0 + hr) * D_IN + hh * 16;

    int lane = t & 63, wv = t >> 6;
    int wm = wv >> 1, wn = wv & 1;
    int lm = lane & 15, q = lane >> 4;

    floatx4 acc[4][4];
    #pragma unroll
    for (int mi = 0; mi < 4; ++mi)
        #pragma unroll
        for (int ni = 0; ni < 4; ++ni)
            acc[mi][ni] = (floatx4){0.f, 0.f, 0.f, 0.f};

    for (int it = 0; it < D_IN / 32; ++it) {
        uint4 a0 = *(const uint4*)(aptr);
        uint4 a1 = *(const uint4*)(aptr + 8);
        uint4 b0 = *(const uint4*)(bptr);
        uint4 b1 = *(const uint4*)(bptr + 8);
        aptr += 32; bptr += 32;

        __syncthreads();
        *(uint4*)(&Ash[hr][hh * 16])     = a0;
        *(uint4*)(&Ash[hr][hh * 16 + 8]) = a1;
        *(uint4*)(&Bsh[hr][hh * 16])     = b0;
        *(uint4*)(&Bsh[hr][hh * 16 + 8]) = b1;
        __syncthreads();

        short8 afr[4];
        #pragma unroll
        for (int mi = 0; mi < 4; ++mi)
            afr[mi] = *(const short8*)(&Ash[wm * 64 + mi * 16 + lm][q * 8]);
        short8 bfr[4];
        #pragma unroll
        for (int ni = 0; ni < 4; ++ni)
            bfr[ni] = *(const short8*)(&Bsh[wn * 64 + ni * 16 + lm][q * 8]);
        #pragma unroll
        for (int mi = 0; mi < 4; ++mi)
            #pragma unroll
            for (int ni = 0; ni < 4; ++ni)
                acc[mi][ni] = __builtin_amdgcn_mfma_f32_16x16x32_bf16(
                    afr[mi], bfr[ni], acc[mi][ni], 0, 0, 0);
    }

    // epilogue: C/D layout col=lane&15, row=(lane>>4)*4+reg
    #pragma unroll
    for (int mi = 0; mi < 4; ++mi) {
        int rbase = wm * 64 + mi * 16 + q * 4;
        #pragma unroll
        for (int r = 0; r < 4; ++r) {
            int row = rbase + r;
            int gi = ty * 128 + row;
            bool ok = gi < n_e;
            int v = rid_sh[row];
            float g = gt_sh[row];
            size_t orow = (size_t)(v >> 1) * D_OUT;
            #pragma unroll
            for (int ni = 0; ni < 4; ++ni) {
                int c = n0 + wn * 64 + ni * 16 + lm;
                float val = g * __expf(acc[mi][ni][r]);
                if (ok) {
                    if (USE_CONTRIB) {
                        float* dst = (v & 1) ? contrib : out;
                        dst[orow + c] = val;
                    } else {
                        atomicAdd(&out[orow + c], val);
                    }
                }
            }
        }
    }
}

// ---------------------------------------------------------------------------
// Fallback f32-input GEMM (used only when ws too small for bf16 buffers).
// ---------------------------------------------------------------------------
template<bool USE_CONTRIB>
__global__ __launch_bounds__(256) void moe_gemm(
        const float* __restrict__ x, const float* __restrict__ w,
        const int* __restrict__ counts, const int* __restrict__ rowlist,
        const float* __restrict__ gatelist,
        float* __restrict__ out, float* __restrict__ contrib) {
    int e = blockIdx.z;
    int n_e = counts[e * CNT_STRIDE];
    int ty = blockIdx.y;
    if (ty * 128 >= n_e) return;
    int n0 = blockIdx.x * 128;

    __shared__ u16_t Ash[128][40];
    __shared__ u32_t Bsh[16][132];
    __shared__ int   rid_sh[128];
    __shared__ float gt_sh[128];

    int t = threadIdx.x;
    if (t < 128) {
        int gi = ty * 128 + t;
        int v = 0; float g = 0.f;
        if (gi < n_e) { v = rowlist[e * B_ROWS + gi]; g = gatelist[e * B_ROWS + gi]; }
        rid_sh[t] = v; gt_sh[t] = g;
    }
    __syncthreads();

    int ar = t >> 1, ah = t & 1;
    const float* xptr = x + (size_t)(rid_sh[ar] >> 1) * D_IN + ah * 16;
    int bkp = t >> 4, bng = t & 15;
    const float* wptr = w + (size_t)e * (D_IN * D_OUT)
                          + (size_t)(2 * bkp) * D_OUT + n0 + bng * 8;

    int lane = t & 63, wv = t >> 6;
    int wm = wv >> 1, wn = wv & 1;
    int lm = lane & 15, q = lane >> 4;

    floatx4 acc[4][4];
    #pragma unroll
    for (int mi = 0; mi < 4; ++mi)
        #pragma unroll
        for (int ni = 0; ni < 4; ++ni)
            acc[mi][ni] = (floatx4){0.f, 0.f, 0.f, 0.f};

    for (int it = 0; it < D_IN / 32; ++it) {
        float4 av0 = *(const float4*)(xptr + 0);
        float4 av1 = *(const float4*)(xptr + 4);
        float4 av2 = *(const float4*)(xptr + 8);
        float4 av3 = *(const float4*)(xptr + 12);
        xptr += 32;
        float4 b0 = *(const float4*)(wptr + 0);
        float4 b1 = *(const float4*)(wptr + 4);
        float4 b2 = *(const float4*)(wptr + D_OUT);
        float4 b3 = *(const float4*)(wptr + D_OUT + 4);
        wptr += 32 * D_OUT;

        __syncthreads();
        {
            union { u16_t us[16]; uint4 v[2]; } ap;
            float af[16] = {av0.x, av0.y, av0.z, av0.w, av1.x, av1.y, av1.z, av1.w,
                            av2.x, av2.y, av2.z, av2.w, av3.x, av3.y, av3.z, av3.w};
            #pragma unroll
            for (int j = 0; j < 16; ++j) ap.us[j] = f2bf(af[j]);
            *(uint4*)(&Ash[ar][ah * 16])     = ap.v[0];
            *(uint4*)(&Ash[ar][ah * 16 + 8]) = ap.v[1];
        }
        {
            union { u32_t up[8]; uint4 v[2]; } bp;
            bp.up[0] = (u32_t)f2bf(b0.x) | ((u32_t)f2bf(b2.x) << 16);
            bp.up[1] = (u32_t)f2bf(b0.y) | ((u32_t)f2bf(b2.y) << 16);
            bp.up[2] = (u32_t)f2bf(b0.z) | ((u32_t)f2bf(b2.z) << 16);
            bp.up[3] = (u32_t)f2bf(b0.w) | ((u32_t)f2bf(b2.w) << 16);
            bp.up[4] = (u32_t)f2bf(b1.x) | ((u32_t)f2bf(b3.x) << 16);
            bp.up[5] = (u32_t)f2bf(b1.y) | ((u32_t)f2bf(b3.y) << 16);
            bp.up[6] = (u32_t)f2bf(b1.z) | ((u32_t)f2bf(b3.z) << 16);
            bp.up[7] = (u32_t)f2bf(b1.w) | ((u32_t)f2bf(b3.w) << 16);
            *(uint4*)(&Bsh[bkp][bng * 8])     = bp.v[0];
            *(uint4*)(&Bsh[bkp][bng * 8 + 4]) = bp.v[1];
        }
        __syncthreads();

        short8 afr[4];
        #pragma unroll
        for (int mi = 0; mi < 4; ++mi)
            afr[mi] = *(const short8*)(&Ash[wm * 64 + mi * 16 + lm][q * 8]);
        short8 bfr[4];
        #pragma unroll
        for (int ni = 0; ni < 4; ++ni) {
            int nn = wn * 64 + ni * 16 + lm;
            union { uint4 u; short8 s; } cv;
            cv.u.x = Bsh[q * 4 + 0][nn];
            cv.u.y = Bsh[q * 4 + 1][nn];
            cv.u.z = Bsh[q * 4 + 2][nn];
            cv.u.w = Bsh[q * 4 + 3][nn];
            bfr[ni] = cv.s;
        }
        #pragma unroll
        for (int mi = 0; mi < 4; ++mi)
            #pragma unroll
            for (int ni = 0; ni < 4; ++ni)
                acc[mi][ni] = __builtin_amdgcn_mfma_f32_16x16x32_bf16(
                    afr[mi], bfr[ni], acc[mi][ni], 0, 0, 0);
    }

    #pragma unroll
    for (int mi = 0; mi < 4; ++mi) {
        int rbase = wm * 64 + mi * 16 + q * 4;
        #pragma unroll
        for (int r = 0; r < 4; ++r) {
            int row = rbase + r;
            int gi = ty * 128 + row;
            bool ok = gi < n_e;
            int v = rid_sh[row];
            float g = gt_sh[row];
            size_t orow = (size_t)(v >> 1) * D_OUT;
            #pragma unroll
            for (int ni = 0; ni < 4; ++ni) {
                int c = n0 + wn * 64 + ni * 16 + lm;
                float val = g * __expf(acc[mi][ni][r]);
                if (ok) {
                    if (USE_CONTRIB) {
                        float* dst = (v & 1) ? contrib : out;
                        dst[orow + c] = val;
                    } else {
                        atomicAdd(&out[orow + c], val);
                    }
                }
            }
        }
    }
}

// ---------------------------------------------------------------------------
// Combine: out = log(clamp(slot0 + slot1, eps))
// ---------------------------------------------------------------------------
__global__ __launch_bounds__(256) void combine_add_log(
        float* __restrict__ out, const float* __restrict__ contrib, int n4) {
    int i = blockIdx.x * blockDim.x + threadIdx.x;
    if (i >= n4) return;
    float4 a = ((const float4*)out)[i];
    float4 b = ((const float4*)contrib)[i];
    float4 r;
    float s;
    s = a.x + b.x; s = (s == 0.f) ? EPSF : s; r.x = __logf(s);
    s = a.y + b.y; s = (s == 0.f) ? EPSF : s; r.y = __logf(s);
    s = a.z + b.z; s = (s == 0.f) ? EPSF : s; r.z = __logf(s);
    s = a.w + b.w; s = (s == 0.f) ? EPSF : s; r.w = __logf(s);
    ((float4*)out)[i] = r;
}

__global__ __launch_bounds__(256) void log_inplace(float* __restrict__ out, int n4) {
    int i = blockIdx.x * blockDim.x + threadIdx.x;
    if (i >= n4) return;
    float4 a = ((float4*)out)[i];
    float4 r;
    float s;
    s = a.x; s = (s == 0.f) ? EPSF : s; r.x = __logf(s);
    s = a.y; s = (s == 0.f) ? EPSF : s; r.y = __logf(s);
    s = a.z; s = (s == 0.f) ? EPSF : s; r.z = __logf(s);
    s = a.w; s = (s == 0.f) ? EPSF : s; r.w = __logf(s);
    ((float4*)out)[i] = r;
}

extern "C" void kernel_launch(void* const* d_in, const int* in_sizes, int n_in,
                              void* d_out, int out_size, void* d_ws, size_t ws_size,
                              hipStream_t stream) {
    const float* x  = (const float*)d_in[0];
    const float* wr = (const float*)d_in[1];
    const float* we = (const float*)d_in[2];
    float* out = (float*)d_out;
    char* ws = (char*)d_ws;

    size_t off = 0;
    int*   counts  = (int*)(ws + off);   off += 1024;                 // 16 x 64B lines
    int*   rowlist = (int*)(ws + off);   off += (size_t)NEXP * B_ROWS * 4;
    float* gates   = (float*)(ws + off); off += (size_t)NEXP * B_ROWS * 4;
    float* wrT     = (float*)(ws + off); off += (size_t)NEXP * D_IN * 4;
    float* contrib = (float*)(ws + off); off += (size_t)B_ROWS * D_OUT * 4;
    size_t tier2_need = off;
    u16_t* xb      = (u16_t*)(ws + off); off += (size_t)B_ROWS * D_IN * 2;
    u16_t* wTb     = (u16_t*)(ws + off); off += (size_t)NEXP * D_IN * D_OUT * 2;
    size_t tier3_need = off;

    hipMemsetAsync(counts, 0, 1024, stream);
    transpose_wr<<<NEXP * D_IN / 256, 256, 0, stream>>>(wr, wrT);
    router_kernel<<<B_ROWS / 32, 256, 0, stream>>>(x, wrT, counts, rowlist, gates);

    dim3 g(D_OUT / 128, B_ROWS / 128, NEXP);
    int n4 = B_ROWS * D_OUT / 4;

    if (ws_size >= tier3_need) {
        convert_x<<<(B_ROWS * D_IN / 8) / 256, 256, 0, stream>>>(x, xb);
        convert_wT<<<NEXP * 128 * 2, 256, 0, stream>>>(we, wTb);
        moe_gemm_bf16<true><<<g, 256, 0, stream>>>(xb, wTb, counts, rowlist, gates, out, contrib);
        combine_add_log<<<(n4 + 255) / 256, 256, 0, stream>>>(out, contrib, n4);
    } else if (ws_size >= tier2_need) {
        moe_gemm<true><<<g, 256, 0, stream>>>(x, we, counts, rowlist, gates, out, contrib);
        combine_add_log<<<(n4 + 255) / 256, 256, 0, stream>>>(out, contrib, n4);
    } else {
        hipMemsetAsync(out, 0, (size_t)B_ROWS * D_OUT * 4, stream);
        moe_gemm<false><<<g, 256, 0, stream>>>(x, we, counts, rowlist, gates, out, nullptr);
        log_inplace<<<(n4 + 255) / 256, 256, 0, stream>>>(out, n4);
    }
}